// Round 1
// baseline (2208.905 us; speedup 1.0000x reference)
//
#include <hip/hip_runtime.h>

typedef __attribute__((ext_vector_type(8))) short bf16x8;
typedef __attribute__((ext_vector_type(4))) short s16x4;
typedef __attribute__((ext_vector_type(4))) float f32x4;

__device__ __forceinline__ float bf2f(unsigned short u) {
    union { unsigned int u; float f; } x; x.u = ((unsigned int)u) << 16; return x.f;
}
__device__ __forceinline__ unsigned short f2bf(float f) {
    union { float f; unsigned int u; } x; x.f = f;
    unsigned int u = x.u;
    unsigned int r = (u + 0x7fffu + ((u >> 16) & 1u)) >> 16;
    return (unsigned short)r;
}

// ---------------------------------------------------------------------------
// GEMM: C[M=32768, N=1024] = A[M,K=1024] @ W^T + bias, W is [N,K] row-major
// bf16 MFMA 16x16x32, tile 128x128, BK=32, 4 waves (each 64x64 = 4x4 frags).
// A either fp32 (cast on the fly) or bf16. Output bf16 or fp32.
// grid = dim3(8 /*N tiles*/, 256 /*M tiles*/), block = 256.
// ---------------------------------------------------------------------------
template<bool A_F32, bool OUT_F32>
__global__ __launch_bounds__(256)
void gemm_bt(const void* __restrict__ A_, const unsigned short* __restrict__ Bw,
             const float* __restrict__ bias, void* __restrict__ out_) {
    __shared__ unsigned short lA[128][40];   // +8 pad: 80B rows -> 2-way conflicts only
    __shared__ unsigned short lB[128][40];
    const int tid  = threadIdx.x;
    const int lane = tid & 63;
    const int wid  = tid >> 6;
    const int wr   = wid >> 1, wc = wid & 1;
    const int  col0 = blockIdx.x * 128;
    const long row0 = (long)blockIdx.y * 128;
    const int sr = tid >> 1;
    const int sc = (tid & 1) * 16;

    f32x4 acc[4][4];
#pragma unroll
    for (int m = 0; m < 4; ++m)
#pragma unroll
        for (int n = 0; n < 4; ++n) acc[m][n] = (f32x4){0.f, 0.f, 0.f, 0.f};

    const float* Af = (const float*)A_;
    const unsigned short* Ab = (const unsigned short*)A_;

    for (int k0 = 0; k0 < 1024; k0 += 32) {
        if constexpr (A_F32) {
            const float* src = Af + (row0 + sr) * 1024 + k0 + sc;
            bf16x8 t0, t1;
#pragma unroll
            for (int q = 0; q < 2; ++q) {
                f32x4 v = *(const f32x4*)(src + 4 * q);
#pragma unroll
                for (int j = 0; j < 4; ++j) t0[4 * q + j] = (short)f2bf(v[j]);
            }
#pragma unroll
            for (int q = 0; q < 2; ++q) {
                f32x4 v = *(const f32x4*)(src + 8 + 4 * q);
#pragma unroll
                for (int j = 0; j < 4; ++j) t1[4 * q + j] = (short)f2bf(v[j]);
            }
            *(bf16x8*)&lA[sr][sc]     = t0;
            *(bf16x8*)&lA[sr][sc + 8] = t1;
        } else {
            const unsigned short* src = Ab + (row0 + sr) * 1024 + k0 + sc;
            *(bf16x8*)&lA[sr][sc]     = *(const bf16x8*)src;
            *(bf16x8*)&lA[sr][sc + 8] = *(const bf16x8*)(src + 8);
        }
        {
            const unsigned short* src = Bw + (long)(col0 + sr) * 1024 + k0 + sc;
            *(bf16x8*)&lB[sr][sc]     = *(const bf16x8*)src;
            *(bf16x8*)&lB[sr][sc + 8] = *(const bf16x8*)(src + 8);
        }
        __syncthreads();

        const int fr = lane & 15, kb = (lane >> 4) * 8;
        bf16x8 aF[4], bF[4];
#pragma unroll
        for (int m = 0; m < 4; ++m) aF[m] = *(const bf16x8*)&lA[wr * 64 + m * 16 + fr][kb];
#pragma unroll
        for (int n = 0; n < 4; ++n) bF[n] = *(const bf16x8*)&lB[wc * 64 + n * 16 + fr][kb];
#pragma unroll
        for (int m = 0; m < 4; ++m)
#pragma unroll
            for (int n = 0; n < 4; ++n)
                acc[m][n] = __builtin_amdgcn_mfma_f32_16x16x32_bf16(aF[m], bF[n], acc[m][n], 0, 0, 0);
        __syncthreads();
    }

    // C/D layout (m89-verified): col = lane&15, row = (lane>>4)*4 + j
    const int cr = (lane >> 4) * 4;
    const int cc = lane & 15;
#pragma unroll
    for (int m = 0; m < 4; ++m) {
        long row = row0 + wr * 64 + m * 16 + cr;
#pragma unroll
        for (int n = 0; n < 4; ++n) {
            int col = col0 + wc * 64 + n * 16 + cc;
            float bv = bias[col];
#pragma unroll
            for (int j = 0; j < 4; ++j) {
                float v = acc[m][n][j] + bv;
                if constexpr (OUT_F32) ((float*)out_)[(row + j) * 1024 + col] = v;
                else ((unsigned short*)out_)[(row + j) * 1024 + col] = f2bf(v);
            }
        }
    }
}

// ---------------------------------------------------------------------------
// In-LDS radix-2 DIT FFT, N=2048, 256 threads. tw[j] = e^{-2*pi*i*j/2048}.
// ---------------------------------------------------------------------------
__device__ __forceinline__ void fft2048(float* zr, float* zi,
                                        const float* twr, const float* twi, int tid) {
    for (int t = tid; t < 2048; t += 256) {
        int j = __brev((unsigned)t) >> 21;
        if (j > t) {
            float a = zr[t]; zr[t] = zr[j]; zr[j] = a;
            float c = zi[t]; zi[t] = zi[j]; zi[j] = c;
        }
    }
    __syncthreads();
    for (int s = 0; s < 11; ++s) {
        const int m = 1 << s;
        for (int i = tid; i < 1024; i += 256) {
            const int pos = i & (m - 1);
            const int i1  = ((i >> s) << (s + 1)) + pos;
            const int i2  = i1 + m;
            const int tw  = pos << (10 - s);
            float wr = twr[tw], wi = twi[tw];
            float xr = zr[i2], xi = zi[i2];
            float tr = wr * xr - wi * xi;
            float ti = wr * xi + wi * xr;
            float ur = zr[i1], ui = zi[i1];
            zr[i2] = ur - tr; zi[i2] = ui - ti;
            zr[i1] = ur + tr; zi[i1] = ui + ti;
        }
        __syncthreads();
    }
}

__device__ __forceinline__ void init_twiddle(float* twr, float* twi, int tid) {
    for (int j = tid; j < 1024; j += 256) {
        float ang = -6.28318530717958647692f * (float)j * (1.0f / 2048.0f);
        twr[j] = cosf(ang);
        twi[j] = sinf(ang);
    }
}

// ---------------------------------------------------------------------------
// Per (b, 8 feature-columns): z = q + i*k, FFT, extract Q,K (Hermitian split),
// accumulate P[f] = Q[f]*conj(K[f]) into per-batch spectrum G[b][1025][2].
// grid = 16*128 blocks.
// ---------------------------------------------------------------------------
__global__ __launch_bounds__(256)
void fft_corr(const unsigned short* __restrict__ qp, const unsigned short* __restrict__ kp,
              float* __restrict__ G) {
    __shared__ float zr[2048], zi[2048];
    __shared__ float twr[1024], twi[1024];
    __shared__ float accR[1025], accI[1025];
    const int tid = threadIdx.x;
    const int b = blockIdx.x >> 7;
    const int chunk = blockIdx.x & 127;

    init_twiddle(twr, twi, tid);
    for (int f = tid; f < 1025; f += 256) { accR[f] = 0.f; accI[f] = 0.f; }

    for (int r = 0; r < 8; ++r) {
        const int d = chunk * 8 + r;
        const unsigned short* qcol = qp + (size_t)b * 2048 * 1024 + d;
        const unsigned short* kcol = kp + (size_t)b * 2048 * 1024 + d;
        for (int t = tid; t < 2048; t += 256) {
            zr[t] = bf2f(qcol[(size_t)t * 1024]);
            zi[t] = bf2f(kcol[(size_t)t * 1024]);
        }
        __syncthreads();
        fft2048(zr, zi, twr, twi, tid);
        for (int f = tid; f < 1025; f += 256) {
            int f2 = (2048 - f) & 2047;
            float Zr = zr[f], Zi = zi[f];
            float Yr = zr[f2], Yi = -zi[f2];           // conj(Z[N-f])
            float Qr = 0.5f * (Zr + Yr), Qi = 0.5f * (Zi + Yi);
            float Kr = 0.5f * (Zi - Yi), Ki = -0.5f * (Zr - Yr);
            accR[f] += Qr * Kr + Qi * Ki;              // Q * conj(K)
            accI[f] += Qi * Kr - Qr * Ki;
        }
        __syncthreads();   // protect z before next row's load
    }
    for (int f = tid; f < 1025; f += 256) {
        atomicAdd(&G[((size_t)b * 1025 + f) * 2 + 0], accR[f]);
        atomicAdd(&G[((size_t)b * 1025 + f) * 2 + 1], accI[f]);
    }
}

// ---------------------------------------------------------------------------
// Per-batch irfft of G -> mean_value[b][t] (length 2048), scale 1/(2048*1024).
// ifft(S)[t] = (1/N)*conj(FFT(conj(S)))[t]; real part only. grid = 16.
// ---------------------------------------------------------------------------
__global__ __launch_bounds__(256)
void irfft_mean(const float* __restrict__ G, float* __restrict__ mv) {
    __shared__ float zr[2048], zi[2048];
    __shared__ float twr[1024], twi[1024];
    const int tid = threadIdx.x;
    const int b = blockIdx.x;
    init_twiddle(twr, twi, tid);
    for (int f = tid; f < 2048; f += 256) {
        int g = (f <= 1024) ? f : 2048 - f;
        float gr = G[((size_t)b * 1025 + g) * 2 + 0];
        float gi = G[((size_t)b * 1025 + g) * 2 + 1];
        zr[f] = gr;
        zi[f] = (f <= 1024) ? -gi : gi;   // conj(S_full)
    }
    __syncthreads();
    fft2048(zr, zi, twr, twi, tid);
    const float sc = 1.0f / (2048.0f * 1024.0f);
    for (int t = tid; t < 2048; t += 256) mv[b * 2048 + t] = zr[t] * sc;
}

// ---------------------------------------------------------------------------
// Top-7 over batch-mean of mean_value, then per-batch softmax of gathered
// weights. Single block, 256 threads.
// ---------------------------------------------------------------------------
__global__ __launch_bounds__(256)
void topk_softmax(const float* __restrict__ mv, int* __restrict__ idx_out,
                  float* __restrict__ w_out) {
    __shared__ float cm[2048];
    __shared__ float bval[256];
    __shared__ int   bidx[256];
    __shared__ int   sel[7];
    const int tid = threadIdx.x;
    for (int t = tid; t < 2048; t += 256) {
        float s = 0.f;
        for (int b = 0; b < 16; ++b) s += mv[b * 2048 + t];
        cm[t] = s * (1.0f / 16.0f);
    }
    __syncthreads();
    for (int it = 0; it < 7; ++it) {
        float best = -3.4e38f; int bi = 1 << 30;
        for (int t = tid; t < 2048; t += 256) {
            float v = cm[t];
            if (v > best || (v == best && t < bi)) { best = v; bi = t; }
        }
        bval[tid] = best; bidx[tid] = bi;
        __syncthreads();
        if (tid == 0) {
            float bb = bval[0]; int bj = bidx[0];
            for (int u = 1; u < 256; ++u)
                if (bval[u] > bb || (bval[u] == bb && bidx[u] < bj)) { bb = bval[u]; bj = bidx[u]; }
            sel[it] = bj;
            idx_out[it] = bj;
            cm[bj] = -3.4e38f;
        }
        __syncthreads();
    }
    if (tid < 16) {
        const int b = tid;
        float wv[7]; float mx = -3.4e38f;
#pragma unroll
        for (int i = 0; i < 7; ++i) { wv[i] = mv[b * 2048 + sel[i]]; mx = fmaxf(mx, wv[i]); }
        float s = 0.f;
#pragma unroll
        for (int i = 0; i < 7; ++i) { wv[i] = expf(wv[i] - mx); s += wv[i]; }
        float inv = 1.0f / s;
#pragma unroll
        for (int i = 0; i < 7; ++i) w_out[b * 7 + i] = wv[i] * inv;
    }
}

// ---------------------------------------------------------------------------
// agg[b,t,d] = sum_i w[b,i] * vp[b,(t+idx[i])%2048,d]  (bf16 in/out)
// grid = dim3(1024, 16): block covers 2 t-rows; thread: 8 d's.
// ---------------------------------------------------------------------------
__global__ __launch_bounds__(256)
void agg_kernel(const unsigned short* __restrict__ vp, const int* __restrict__ idx,
                const float* __restrict__ w, unsigned short* __restrict__ agg) {
    const int b  = blockIdx.y;
    const int t  = blockIdx.x * 2 + (threadIdx.x >> 7);
    const int d8 = (threadIdx.x & 127) * 8;
    float av[8] = {0.f, 0.f, 0.f, 0.f, 0.f, 0.f, 0.f, 0.f};
#pragma unroll
    for (int i = 0; i < 7; ++i) {
        const int srow = (t + idx[i]) & 2047;
        const float wi = w[b * 7 + i];
        bf16x8 v = *(const bf16x8*)&vp[((size_t)b * 2048 + srow) * 1024 + d8];
#pragma unroll
        for (int j = 0; j < 8; ++j) av[j] += wi * bf2f((unsigned short)v[j]);
    }
    bf16x8 o;
#pragma unroll
    for (int j = 0; j < 8; ++j) o[j] = (short)f2bf(av[j]);
    *(bf16x8*)&agg[((size_t)b * 2048 + t) * 1024 + d8] = o;
}

// ---------------------------------------------------------------------------
__global__ __launch_bounds__(256)
void cast_w(const float* __restrict__ src, unsigned short* __restrict__ dst) {
    const int i = (blockIdx.x * 256 + threadIdx.x) * 4;   // n = 1048576 exact
    f32x4 v = *(const f32x4*)(src + i);
    s16x4 o;
#pragma unroll
    for (int j = 0; j < 4; ++j) o[j] = (short)f2bf(v[j]);
    *(s16x4*)(dst + i) = o;
}

__global__ __launch_bounds__(256)
void zero_f32(float* __restrict__ p, int n) {
    const int i = blockIdx.x * 256 + threadIdx.x;
    if (i < n) p[i] = 0.0f;
}

// ---------------------------------------------------------------------------
extern "C" void kernel_launch(void* const* d_in, const int* in_sizes, int n_in,
                              void* d_out, int out_size, void* d_ws, size_t ws_size,
                              hipStream_t stream) {
    const float* queries = (const float*)d_in[0];
    const float* keys    = (const float*)d_in[1];
    const float* values  = (const float*)d_in[2];
    const float* Wq = (const float*)d_in[3];  const float* bq = (const float*)d_in[4];
    const float* Wk = (const float*)d_in[5];  const float* bk = (const float*)d_in[6];
    const float* Wv = (const float*)d_in[7];  const float* bv = (const float*)d_in[8];
    const float* Wo = (const float*)d_in[9];  const float* bo = (const float*)d_in[10];
    float* out = (float*)d_out;

    char* ws = (char*)d_ws;
    constexpr size_t SZP = (size_t)32768 * 1024 * 2;           // 64 MB (bf16 B*L*D)
    unsigned short* qp  = (unsigned short*)(ws);               // also reused as agg
    unsigned short* kp  = (unsigned short*)(ws + SZP);
    unsigned short* vp  = (unsigned short*)(ws + 2 * SZP);
    unsigned short* w16 = (unsigned short*)(ws + 3 * SZP);     // 4 x 1M bf16
    float* G   = (float*)(ws + 3 * SZP + 8388608);             // 16*1025*2 f32
    float* mv  = (float*)(ws + 3 * SZP + 8388608 + 131328);    // 16*2048 f32
    int*   idx = (int*)  (ws + 3 * SZP + 8388608 + 131328 + 131072);
    float* wsm = (float*)(ws + 3 * SZP + 8388608 + 131328 + 131072 + 64);
    unsigned short* agg = qp;

    cast_w<<<1024, 256, 0, stream>>>(Wq, w16 + 0 * 1048576);
    cast_w<<<1024, 256, 0, stream>>>(Wk, w16 + 1 * 1048576);
    cast_w<<<1024, 256, 0, stream>>>(Wv, w16 + 2 * 1048576);
    cast_w<<<1024, 256, 0, stream>>>(Wo, w16 + 3 * 1048576);
    zero_f32<<<(32800 + 255) / 256, 256, 0, stream>>>(G, 32800);

    gemm_bt<true, false><<<dim3(8, 256), 256, 0, stream>>>(queries, w16 + 0 * 1048576, bq, qp);
    gemm_bt<true, false><<<dim3(8, 256), 256, 0, stream>>>(keys,    w16 + 1 * 1048576, bk, kp);
    gemm_bt<true, false><<<dim3(8, 256), 256, 0, stream>>>(values,  w16 + 2 * 1048576, bv, vp);

    fft_corr<<<2048, 256, 0, stream>>>(qp, kp, G);
    irfft_mean<<<16, 256, 0, stream>>>(G, mv);
    topk_softmax<<<1, 256, 0, stream>>>(mv, idx, wsm);
    agg_kernel<<<dim3(1024, 16), 256, 0, stream>>>(vp, idx, wsm, agg);

    gemm_bt<false, true><<<dim3(8, 256), 256, 0, stream>>>(agg, w16 + 3 * 1048576, bo, out);
}

// Round 2
// 984.397 us; speedup vs baseline: 2.2439x; 2.2439x over previous
//
#include <hip/hip_runtime.h>

typedef __attribute__((ext_vector_type(8))) short bf16x8;
typedef __attribute__((ext_vector_type(4))) short s16x4;
typedef __attribute__((ext_vector_type(4))) float f32x4;

__device__ __forceinline__ float bf2f(unsigned short u) {
    union { unsigned int u; float f; } x; x.u = ((unsigned int)u) << 16; return x.f;
}
__device__ __forceinline__ unsigned short f2bf(float f) {
    union { float f; unsigned int u; } x; x.f = f;
    unsigned int u = x.u;
    unsigned int r = (u + 0x7fffu + ((u >> 16) & 1u)) >> 16;
    return (unsigned short)r;
}

// ---------------------------------------------------------------------------
// GEMM: C[M=32768, N=1024] = A[M,K=1024] @ W^T + bias, W is [N,K] row-major
// bf16 MFMA 16x16x32, tile 128x128, BK=32, 4 waves (each 64x64 = 4x4 frags).
// OUT_MODE: 0 = bf16 [b,t,d], 1 = f32 [b,t,d], 2 = bf16 transposed [b,d,t]
// grid = dim3(8 /*N tiles*/, 256 /*M tiles*/), block = 256.
// ---------------------------------------------------------------------------
template<bool A_F32, int OUT_MODE>
__global__ __launch_bounds__(256)
void gemm_bt(const void* __restrict__ A_, const unsigned short* __restrict__ Bw,
             const float* __restrict__ bias, void* __restrict__ out_) {
    __shared__ unsigned short lA[128][40];   // +8 pad: 2-way conflicts only
    __shared__ unsigned short lB[128][40];
    const int tid  = threadIdx.x;
    const int lane = tid & 63;
    const int wid  = tid >> 6;
    const int wr   = wid >> 1, wc = wid & 1;
    const int  col0 = blockIdx.x * 128;
    const long row0 = (long)blockIdx.y * 128;
    const int sr = tid >> 1;
    const int sc = (tid & 1) * 16;

    f32x4 acc[4][4];
#pragma unroll
    for (int m = 0; m < 4; ++m)
#pragma unroll
        for (int n = 0; n < 4; ++n) acc[m][n] = (f32x4){0.f, 0.f, 0.f, 0.f};

    const float* Af = (const float*)A_;
    const unsigned short* Ab = (const unsigned short*)A_;

    for (int k0 = 0; k0 < 1024; k0 += 32) {
        if constexpr (A_F32) {
            const float* src = Af + (row0 + sr) * 1024 + k0 + sc;
            bf16x8 t0, t1;
#pragma unroll
            for (int q = 0; q < 2; ++q) {
                f32x4 v = *(const f32x4*)(src + 4 * q);
#pragma unroll
                for (int j = 0; j < 4; ++j) t0[4 * q + j] = (short)f2bf(v[j]);
            }
#pragma unroll
            for (int q = 0; q < 2; ++q) {
                f32x4 v = *(const f32x4*)(src + 8 + 4 * q);
#pragma unroll
                for (int j = 0; j < 4; ++j) t1[4 * q + j] = (short)f2bf(v[j]);
            }
            *(bf16x8*)&lA[sr][sc]     = t0;
            *(bf16x8*)&lA[sr][sc + 8] = t1;
        } else {
            const unsigned short* src = Ab + (row0 + sr) * 1024 + k0 + sc;
            *(bf16x8*)&lA[sr][sc]     = *(const bf16x8*)src;
            *(bf16x8*)&lA[sr][sc + 8] = *(const bf16x8*)(src + 8);
        }
        {
            const unsigned short* src = Bw + (long)(col0 + sr) * 1024 + k0 + sc;
            *(bf16x8*)&lB[sr][sc]     = *(const bf16x8*)src;
            *(bf16x8*)&lB[sr][sc + 8] = *(const bf16x8*)(src + 8);
        }
        __syncthreads();

        const int fr = lane & 15, kb = (lane >> 4) * 8;
        bf16x8 aF[4], bF[4];
#pragma unroll
        for (int m = 0; m < 4; ++m) aF[m] = *(const bf16x8*)&lA[wr * 64 + m * 16 + fr][kb];
#pragma unroll
        for (int n = 0; n < 4; ++n) bF[n] = *(const bf16x8*)&lB[wc * 64 + n * 16 + fr][kb];
#pragma unroll
        for (int m = 0; m < 4; ++m)
#pragma unroll
            for (int n = 0; n < 4; ++n)
                acc[m][n] = __builtin_amdgcn_mfma_f32_16x16x32_bf16(aF[m], bF[n], acc[m][n], 0, 0, 0);
        __syncthreads();
    }

    // C/D layout (m89-verified): col = lane&15, row = (lane>>4)*4 + j
    const int cr = (lane >> 4) * 4;
    const int cc = lane & 15;
    if constexpr (OUT_MODE == 2) {
        // transposed bf16 store: out[b][col][t], 4 consecutive t per thread = 8B store
        const int b  = (int)(row0 >> 11);
        const int tb = ((int)row0 & 2047) + wr * 64 + cr;
#pragma unroll
        for (int m = 0; m < 4; ++m) {
#pragma unroll
            for (int n = 0; n < 4; ++n) {
                int col = col0 + wc * 64 + n * 16 + cc;
                float bv = bias[col];
                s16x4 o;
#pragma unroll
                for (int j = 0; j < 4; ++j) o[j] = (short)f2bf(acc[m][n][j] + bv);
                *(s16x4*)&((unsigned short*)out_)[((size_t)b * 1024 + col) * 2048 + tb + m * 16] = o;
            }
        }
    } else {
#pragma unroll
        for (int m = 0; m < 4; ++m) {
            long row = row0 + wr * 64 + m * 16 + cr;
#pragma unroll
            for (int n = 0; n < 4; ++n) {
                int col = col0 + wc * 64 + n * 16 + cc;
                float bv = bias[col];
#pragma unroll
                for (int j = 0; j < 4; ++j) {
                    float v = acc[m][n][j] + bv;
                    if constexpr (OUT_MODE == 1) ((float*)out_)[(row + j) * 1024 + col] = v;
                    else ((unsigned short*)out_)[(row + j) * 1024 + col] = f2bf(v);
                }
            }
        }
    }
}

// ---------------------------------------------------------------------------
// 8-point DFT (negative exponent), in place on xr/xi[8].
// ---------------------------------------------------------------------------
__device__ __forceinline__ void dft8(float* xr, float* xi) {
    const float c8 = 0.70710678118654752440f;
    float es0r = xr[0] + xr[4], es0i = xi[0] + xi[4];
    float es1r = xr[0] - xr[4], es1i = xi[0] - xi[4];
    float es2r = xr[2] + xr[6], es2i = xi[2] + xi[6];
    float es3r = xr[2] - xr[6], es3i = xi[2] - xi[6];
    float E0r = es0r + es2r, E0i = es0i + es2i;
    float E2r = es0r - es2r, E2i = es0i - es2i;
    float E1r = es1r + es3i, E1i = es1i - es3r;
    float E3r = es1r - es3i, E3i = es1i + es3r;
    float os0r = xr[1] + xr[5], os0i = xi[1] + xi[5];
    float os1r = xr[1] - xr[5], os1i = xi[1] - xi[5];
    float os2r = xr[3] + xr[7], os2i = xi[3] + xi[7];
    float os3r = xr[3] - xr[7], os3i = xi[3] - xi[7];
    float O0r = os0r + os2r, O0i = os0i + os2i;
    float O2r = os0r - os2r, O2i = os0i - os2i;
    float O1r = os1r + os3i, O1i = os1i - os3r;
    float O3r = os1r - os3i, O3i = os1i + os3r;
    float p1 = c8 * (O1r + O1i), q1 = c8 * (O1i - O1r);
    float p3 = c8 * (O3r + O3i), q3 = c8 * (O3i - O3r);
    xr[0] = E0r + O0r; xi[0] = E0i + O0i;
    xr[4] = E0r - O0r; xi[4] = E0i - O0i;
    xr[1] = E1r + p1;  xi[1] = E1i + q1;
    xr[5] = E1r - p1;  xi[5] = E1i - q1;
    xr[2] = E2r + O2i; xi[2] = E2i - O2r;
    xr[6] = E2r - O2i; xi[6] = E2i + O2r;
    xr[3] = E3r + q3;  xi[3] = E3i - p3;
    xr[7] = E3r - q3;  xi[7] = E3i + p3;
}

__device__ __forceinline__ int padc(int p) { return p + (p >> 5); }

// ---------------------------------------------------------------------------
// fft_corr: per (b, 8 d-columns): z = q + i*k read COALESCED from transposed
// layout qt/kt[b][d][t]; register-blocked mixed-radix FFT (8*8*8*4):
// 3 radix-8 rounds + radix-4, 3 LDS exchanges + natural-order scatter;
// Hermitian split -> accumulate P = Q*conj(K) into G[b][1025][2].
// grid = 2048 (16 b x 128 chunks), block = 256.
// ---------------------------------------------------------------------------
__global__ __launch_bounds__(256)
void fft_corr(const unsigned short* __restrict__ qt, const unsigned short* __restrict__ kt,
              float* __restrict__ G) {
    __shared__ float2 zc[2112];                 // padded 2048 complex
    __shared__ float accR[1025], accI[1025];
    float* zfr = (float*)zc;                    // aliased natural-order output
    float* zfi = zfr + 2112;
    const int tid = threadIdx.x;
    const int b = blockIdx.x >> 7;
    const int chunk = blockIdx.x & 127;

    // thread-constant twiddle bases
    const float N2PI = -6.28318530717958647692f;
    float w1r, w1i, w2r, w2i, w3r, w3i;
    {
        float s, c;
        __sincosf(N2PI * (float)tid * (1.0f / 2048.0f), &s, &c); w1r = c; w1i = s;
        __sincosf(N2PI * (float)(tid & 31) * (1.0f / 256.0f), &s, &c); w2r = c; w2i = s;
        __sincosf(N2PI * (float)(tid & 3) * (1.0f / 32.0f),  &s, &c); w3r = c; w3i = s;
    }

    for (int f = tid; f < 1025; f += 256) { accR[f] = 0.f; accI[f] = 0.f; }
    // acc entries are owner-computed (f = tid + 256k) -> no barrier needed here

    const int beta = tid >> 5, s2 = tid & 31;
    const int gam  = tid >> 2, u3 = tid & 3;

    for (int r = 0; r < 8; ++r) {
        const int d = chunk * 8 + r;
        const unsigned short* qrow = qt + ((size_t)b * 1024 + d) * 2048;
        const unsigned short* krow = kt + ((size_t)b * 1024 + d) * 2048;

        float xr[8], xi[8];
        // ----- Round 1: thread t holds z[t + 256k]; coalesced 2B loads -----
#pragma unroll
        for (int k = 0; k < 8; ++k) {
            xr[k] = bf2f(qrow[tid + 256 * k]);
            xi[k] = bf2f(krow[tid + 256 * k]);
        }
        dft8(xr, xi);
        {   // twiddle W_2048^{t*k}, chained powers of w1
            float cr_ = w1r, ci_ = w1i;
#pragma unroll
            for (int k = 1; k < 8; ++k) {
                float tr = xr[k] * cr_ - xi[k] * ci_;
                float ti = xr[k] * ci_ + xi[k] * cr_;
                xr[k] = tr; xi[k] = ti;
                if (k < 7) {
                    float nr = cr_ * w1r - ci_ * w1i;
                    float ni = cr_ * w1i + ci_ * w1r;
                    cr_ = nr; ci_ = ni;
                }
            }
        }
#pragma unroll
        for (int k = 0; k < 8; ++k) zc[padc(256 * k + tid)] = make_float2(xr[k], xi[k]);
        __syncthreads();

        // ----- Round 2: 8 independent 256-DFTs; thread: block beta, pos s2+32k
#pragma unroll
        for (int k = 0; k < 8; ++k) {
            float2 v = zc[padc(256 * beta + 32 * k + s2)];
            xr[k] = v.x; xi[k] = v.y;
        }
        __syncthreads();
        dft8(xr, xi);
        {   // twiddle W_256^{s2*k}
            float cr_ = w2r, ci_ = w2i;
#pragma unroll
            for (int k = 1; k < 8; ++k) {
                float tr = xr[k] * cr_ - xi[k] * ci_;
                float ti = xr[k] * ci_ + xi[k] * cr_;
                xr[k] = tr; xi[k] = ti;
                if (k < 7) {
                    float nr = cr_ * w2r - ci_ * w2i;
                    float ni = cr_ * w2i + ci_ * w2r;
                    cr_ = nr; ci_ = ni;
                }
            }
        }
#pragma unroll
        for (int k = 0; k < 8; ++k) zc[padc(256 * beta + 32 * k + s2)] = make_float2(xr[k], xi[k]);
        __syncthreads();

        // ----- Round 3: 64 independent 32-DFTs; thread: block gam, pos u3+4k
#pragma unroll
        for (int k = 0; k < 8; ++k) {
            float2 v = zc[padc(32 * gam + 4 * k + u3)];
            xr[k] = v.x; xi[k] = v.y;
        }
        __syncthreads();
        dft8(xr, xi);
        {   // twiddle W_32^{u3*k}
            float cr_ = w3r, ci_ = w3i;
#pragma unroll
            for (int k = 1; k < 8; ++k) {
                float tr = xr[k] * cr_ - xi[k] * ci_;
                float ti = xr[k] * ci_ + xi[k] * cr_;
                xr[k] = tr; xi[k] = ti;
                if (k < 7) {
                    float nr = cr_ * w3r - ci_ * w3i;
                    float ni = cr_ * w3i + ci_ * w3r;
                    cr_ = nr; ci_ = ni;
                }
            }
        }
#pragma unroll
        for (int k = 0; k < 8; ++k) zc[padc(32 * gam + 4 * k + u3)] = make_float2(xr[k], xi[k]);
        __syncthreads();

        // ----- Round 4: 512 contiguous 4-DFTs; thread reads pos 8t..8t+7 -----
#pragma unroll
        for (int k = 0; k < 8; ++k) {
            float2 v = zc[padc(8 * tid + k)];
            xr[k] = v.x; xi[k] = v.y;
        }
        __syncthreads();   // all zc reads done before aliased zfr/zfi writes

        // two radix-4 DFTs (no twiddle): X0=s0+s2, X2=s0-s2, X1=s1-i*s3, X3=s1+i*s3
        float Xr[8], Xi[8];
#pragma unroll
        for (int blk = 0; blk < 2; ++blk) {
            const int o = 4 * blk;
            float s0r = xr[o] + xr[o + 2], s0i = xi[o] + xi[o + 2];
            float s1r = xr[o] - xr[o + 2], s1i = xi[o] - xi[o + 2];
            float s2r = xr[o + 1] + xr[o + 3], s2i = xi[o + 1] + xi[o + 3];
            float s3r = xr[o + 1] - xr[o + 3], s3i = xi[o + 1] - xi[o + 3];
            Xr[o + 0] = s0r + s2r; Xi[o + 0] = s0i + s2i;
            Xr[o + 2] = s0r - s2r; Xi[o + 2] = s0i - s2i;
            Xr[o + 1] = s1r + s3i; Xi[o + 1] = s1i - s3r;
            Xr[o + 3] = s1r - s3i; Xi[o + 3] = s1i + s3r;
        }
        // scatter to natural frequency order:
        // pos = 8t+j (j=u digit pre-DFT): k1=t>>5, k2=(t>>2)&7, k3=(2(t&3)+(j>>2))&7
        // output f = k1 + 8*k2 + 64*k3 + 512*k4  (k4 = output index of the 4-DFT)
        {
            const int k1 = tid >> 5;
            const int k2 = (tid >> 2) & 7;
            const int fb = k1 + 8 * k2;
#pragma unroll
            for (int blk = 0; blk < 2; ++blk) {
                const int k3 = (2 * (tid & 3) + blk) & 7;
#pragma unroll
                for (int k4 = 0; k4 < 4; ++k4) {
                    const int f = fb + 64 * k3 + 512 * k4;
                    const int pf = padc(f);
                    zfr[pf] = Xr[4 * blk + k4];
                    zfi[pf] = Xi[4 * blk + k4];
                }
            }
        }
        __syncthreads();

        // ----- Hermitian split + accumulate P = Q * conj(K) -----
        for (int f = tid; f < 1025; f += 256) {
            const int f2 = (2048 - f) & 2047;
            const int pf = padc(f), pf2 = padc(f2);
            float Zr = zfr[pf],  Zi = zfi[pf];
            float Yr = zfr[pf2], Yi = -zfi[pf2];       // conj(Z[N-f])
            float Qr = 0.5f * (Zr + Yr), Qi = 0.5f * (Zi + Yi);
            float Kr = 0.5f * (Zi - Yi), Ki = -0.5f * (Zr - Yr);
            accR[f] += Qr * Kr + Qi * Ki;
            accI[f] += Qi * Kr - Qr * Ki;
        }
        __syncthreads();   // zfr/zfi (alias zc) reads done before next R1 write
    }

    for (int f = tid; f < 1025; f += 256) {
        atomicAdd(&G[((size_t)b * 1025 + f) * 2 + 0], accR[f]);
        atomicAdd(&G[((size_t)b * 1025 + f) * 2 + 1], accI[f]);
    }
}

// ---------------------------------------------------------------------------
// In-LDS radix-2 DIT FFT, N=2048 (only used by irfft_mean: 16 blocks, cheap).
// ---------------------------------------------------------------------------
__device__ __forceinline__ void fft2048(float* zr, float* zi,
                                        const float* twr, const float* twi, int tid) {
    for (int t = tid; t < 2048; t += 256) {
        int j = __brev((unsigned)t) >> 21;
        if (j > t) {
            float a = zr[t]; zr[t] = zr[j]; zr[j] = a;
            float c = zi[t]; zi[t] = zi[j]; zi[j] = c;
        }
    }
    __syncthreads();
    for (int s = 0; s < 11; ++s) {
        const int m = 1 << s;
        for (int i = tid; i < 1024; i += 256) {
            const int pos = i & (m - 1);
            const int i1  = ((i >> s) << (s + 1)) + pos;
            const int i2  = i1 + m;
            const int tw  = pos << (10 - s);
            float wr = twr[tw], wi = twi[tw];
            float xr = zr[i2], xi = zi[i2];
            float tr = wr * xr - wi * xi;
            float ti = wr * xi + wi * xr;
            float ur = zr[i1], ui = zi[i1];
            zr[i2] = ur - tr; zi[i2] = ui - ti;
            zr[i1] = ur + tr; zi[i1] = ui + ti;
        }
        __syncthreads();
    }
}

__device__ __forceinline__ void init_twiddle(float* twr, float* twi, int tid) {
    for (int j = tid; j < 1024; j += 256) {
        float ang = -6.28318530717958647692f * (float)j * (1.0f / 2048.0f);
        twr[j] = cosf(ang);
        twi[j] = sinf(ang);
    }
}

// ---------------------------------------------------------------------------
// Per-batch irfft of G -> mean_value[b][t], scale 1/(2048*1024). grid = 16.
// ---------------------------------------------------------------------------
__global__ __launch_bounds__(256)
void irfft_mean(const float* __restrict__ G, float* __restrict__ mv) {
    __shared__ float zr[2048], zi[2048];
    __shared__ float twr[1024], twi[1024];
    const int tid = threadIdx.x;
    const int b = blockIdx.x;
    init_twiddle(twr, twi, tid);
    for (int f = tid; f < 2048; f += 256) {
        int g = (f <= 1024) ? f : 2048 - f;
        float gr = G[((size_t)b * 1025 + g) * 2 + 0];
        float gi = G[((size_t)b * 1025 + g) * 2 + 1];
        zr[f] = gr;
        zi[f] = (f <= 1024) ? -gi : gi;   // conj(S_full)
    }
    __syncthreads();
    fft2048(zr, zi, twr, twi, tid);
    const float sc = 1.0f / (2048.0f * 1024.0f);
    for (int t = tid; t < 2048; t += 256) mv[b * 2048 + t] = zr[t] * sc;
}

// ---------------------------------------------------------------------------
// Top-7 over batch-mean of mean_value + per-batch softmax of gathered weights.
// ---------------------------------------------------------------------------
__global__ __launch_bounds__(256)
void topk_softmax(const float* __restrict__ mv, int* __restrict__ idx_out,
                  float* __restrict__ w_out) {
    __shared__ float cm[2048];
    __shared__ float bval[256];
    __shared__ int   bidx[256];
    __shared__ int   sel[7];
    const int tid = threadIdx.x;
    for (int t = tid; t < 2048; t += 256) {
        float s = 0.f;
        for (int b = 0; b < 16; ++b) s += mv[b * 2048 + t];
        cm[t] = s * (1.0f / 16.0f);
    }
    __syncthreads();
    for (int it = 0; it < 7; ++it) {
        float best = -3.4e38f; int bi = 1 << 30;
        for (int t = tid; t < 2048; t += 256) {
            float v = cm[t];
            if (v > best || (v == best && t < bi)) { best = v; bi = t; }
        }
        bval[tid] = best; bidx[tid] = bi;
        __syncthreads();
        if (tid == 0) {
            float bb = bval[0]; int bj = bidx[0];
            for (int u = 1; u < 256; ++u)
                if (bval[u] > bb || (bval[u] == bb && bidx[u] < bj)) { bb = bval[u]; bj = bidx[u]; }
            sel[it] = bj;
            idx_out[it] = bj;
            cm[bj] = -3.4e38f;
        }
        __syncthreads();
    }
    if (tid < 16) {
        const int b = tid;
        float wv[7]; float mx = -3.4e38f;
#pragma unroll
        for (int i = 0; i < 7; ++i) { wv[i] = mv[b * 2048 + sel[i]]; mx = fmaxf(mx, wv[i]); }
        float s = 0.f;
#pragma unroll
        for (int i = 0; i < 7; ++i) { wv[i] = expf(wv[i] - mx); s += wv[i]; }
        float inv = 1.0f / s;
#pragma unroll
        for (int i = 0; i < 7; ++i) w_out[b * 7 + i] = wv[i] * inv;
    }
}

// ---------------------------------------------------------------------------
// agg[b,t,d] = sum_i w[b,i] * vp[b,(t+idx[i])%2048,d]  (bf16 in/out)
// ---------------------------------------------------------------------------
__global__ __launch_bounds__(256)
void agg_kernel(const unsigned short* __restrict__ vp, const int* __restrict__ idx,
                const float* __restrict__ w, unsigned short* __restrict__ agg) {
    const int b  = blockIdx.y;
    const int t  = blockIdx.x * 2 + (threadIdx.x >> 7);
    const int d8 = (threadIdx.x & 127) * 8;
    float av[8] = {0.f, 0.f, 0.f, 0.f, 0.f, 0.f, 0.f, 0.f};
#pragma unroll
    for (int i = 0; i < 7; ++i) {
        const int srow = (t + idx[i]) & 2047;
        const float wi = w[b * 7 + i];
        bf16x8 v = *(const bf16x8*)&vp[((size_t)b * 2048 + srow) * 1024 + d8];
#pragma unroll
        for (int j = 0; j < 8; ++j) av[j] += wi * bf2f((unsigned short)v[j]);
    }
    bf16x8 o;
#pragma unroll
    for (int j = 0; j < 8; ++j) o[j] = (short)f2bf(av[j]);
    *(bf16x8*)&agg[((size_t)b * 2048 + t) * 1024 + d8] = o;
}

// ---------------------------------------------------------------------------
__global__ __launch_bounds__(256)
void cast_w(const float* __restrict__ src, unsigned short* __restrict__ dst) {
    const int i = (blockIdx.x * 256 + threadIdx.x) * 4;   // n = 1048576 exact
    f32x4 v = *(const f32x4*)(src + i);
    s16x4 o;
#pragma unroll
    for (int j = 0; j < 4; ++j) o[j] = (short)f2bf(v[j]);
    *(s16x4*)(dst + i) = o;
}

__global__ __launch_bounds__(256)
void zero_f32(float* __restrict__ p, int n) {
    const int i = blockIdx.x * 256 + threadIdx.x;
    if (i < n) p[i] = 0.0f;
}

// ---------------------------------------------------------------------------
extern "C" void kernel_launch(void* const* d_in, const int* in_sizes, int n_in,
                              void* d_out, int out_size, void* d_ws, size_t ws_size,
                              hipStream_t stream) {
    const float* queries = (const float*)d_in[0];
    const float* keys    = (const float*)d_in[1];
    const float* values  = (const float*)d_in[2];
    const float* Wq = (const float*)d_in[3];  const float* bq = (const float*)d_in[4];
    const float* Wk = (const float*)d_in[5];  const float* bk = (const float*)d_in[6];
    const float* Wv = (const float*)d_in[7];  const float* bv = (const float*)d_in[8];
    const float* Wo = (const float*)d_in[9];  const float* bo = (const float*)d_in[10];
    float* out = (float*)d_out;

    char* ws = (char*)d_ws;
    constexpr size_t SZP = (size_t)32768 * 1024 * 2;           // 64 MB (bf16 B*L*D)
    unsigned short* qt  = (unsigned short*)(ws);               // [b][d][t]; reused as agg
    unsigned short* kt  = (unsigned short*)(ws + SZP);         // [b][d][t]
    unsigned short* vp  = (unsigned short*)(ws + 2 * SZP);     // [b][t][d]
    unsigned short* w16 = (unsigned short*)(ws + 3 * SZP);     // 4 x 1M bf16
    float* G   = (float*)(ws + 3 * SZP + 8388608);             // 16*1025*2 f32
    float* mv  = (float*)(ws + 3 * SZP + 8388608 + 131328);    // 16*2048 f32
    int*   idx = (int*)  (ws + 3 * SZP + 8388608 + 131328 + 131072);
    float* wsm = (float*)(ws + 3 * SZP + 8388608 + 131328 + 131072 + 64);
    unsigned short* agg = qt;

    cast_w<<<1024, 256, 0, stream>>>(Wq, w16 + 0 * 1048576);
    cast_w<<<1024, 256, 0, stream>>>(Wk, w16 + 1 * 1048576);
    cast_w<<<1024, 256, 0, stream>>>(Wv, w16 + 2 * 1048576);
    cast_w<<<1024, 256, 0, stream>>>(Wo, w16 + 3 * 1048576);
    zero_f32<<<(32800 + 255) / 256, 256, 0, stream>>>(G, 32800);

    gemm_bt<true, 2><<<dim3(8, 256), 256, 0, stream>>>(queries, w16 + 0 * 1048576, bq, qt);
    gemm_bt<true, 2><<<dim3(8, 256), 256, 0, stream>>>(keys,    w16 + 1 * 1048576, bk, kt);
    gemm_bt<true, 0><<<dim3(8, 256), 256, 0, stream>>>(values,  w16 + 2 * 1048576, bv, vp);

    fft_corr<<<2048, 256, 0, stream>>>(qt, kt, G);
    irfft_mean<<<16, 256, 0, stream>>>(G, mv);
    topk_softmax<<<1, 256, 0, stream>>>(mv, idx, wsm);
    agg_kernel<<<dim3(1024, 16), 256, 0, stream>>>(vp, idx, wsm, agg);

    gemm_bt<false, 1><<<dim3(8, 256), 256, 0, stream>>>(agg, w16 + 3 * 1048576, bo, out);
}